// Round 6
// baseline (74642.297 us; speedup 1.0000x reference)
//
#include <hip/hip_runtime.h>
#include <math.h>

// ---------------- problem constants ----------------
constexpr int TT = 256, BB = 16, DD = 512;
constexpr int NTOK = 4096;                 // T*B
constexpr int RTOT = 3456;                 // 768 + 384 + 768 + 1536
constexpr int E1OFF = 768, E2OFF = 1152, E3OFF = 1920;

// ---------------- workspace layout (bytes) ----------------
constexpr size_t OFF_TSUM  = 0;                                  // 4 f
constexpr size_t OFF_TCNT  = 16;                                 // 4 f
constexpr size_t OFF_CNT   = 32;                                 // 8 ints (XCD claim)
constexpr size_t OFF_FR    = 1024;                               // 16 uint flags (router)
constexpr size_t OFF_F3    = 1152;                               // 16 uint flags (E3)
constexpr size_t OFF_F2    = 1280;                               // 8 uint flags (E2)
constexpr size_t ZBYTES    = 2048;                               // memset 0 range
constexpr size_t OFF_RINGR = 8192;                               // 4*4096*4 = 64 KB
constexpr size_t OFF_RING3 = OFF_RINGR + 4ull*4096*4;            // 4*512*4 = 8 KB
constexpr size_t OFF_RING2 = OFF_RING3 + 4ull*512*4;             // 4*256*4 = 4 KB
constexpr size_t OFF_GI   = 131072;
constexpr size_t OFF_HS   = OFF_GI  + (size_t)NTOK*RTOT*4;
constexpr size_t OFF_HA3  = OFF_HS  + (size_t)NTOK*256*4;
constexpr size_t OFF_HA2  = OFF_HA3 + (size_t)NTOK*512*4;
constexpr size_t OFF_HA1  = OFF_HA2 + (size_t)NTOK*256*4;
constexpr size_t OFF_AP   = OFF_HA1 + (size_t)NTOK*128*4;
constexpr size_t OFF_MU   = OFF_AP  + (size_t)NTOK*896*4;
constexpr size_t OFF_RSTD = OFF_MU  + 896*4;

__device__ __forceinline__ float sigm(float x) { return 1.f / (1.f + expf(-x)); }

// ================= phase 1: gi = x @ Wih^T + b_ih (all 3456 rows) =================
__global__ __launch_bounds__(256) void gemm1_kernel(
    const float* __restrict__ X,
    const float* __restrict__ wR, const float* __restrict__ w1,
    const float* __restrict__ w2, const float* __restrict__ w3,
    const float* __restrict__ bR, const float* __restrict__ b1,
    const float* __restrict__ b2, const float* __restrict__ b3,
    float* __restrict__ GI)
{
  __shared__ float At[32*64];
  __shared__ float Bt[32*64];
  const int n0 = blockIdx.x * 64;
  const int r0 = blockIdx.y * 64;
  const float* W; const float* bias; int rs;
  if (r0 < 768)       { W = wR; bias = bR; rs = 0; }
  else if (r0 < 1152) { W = w1; bias = b1; rs = 768; }
  else if (r0 < 1920) { W = w2; bias = b2; rs = 1152; }
  else                { W = w3; bias = b3; rs = 1920; }
  const int lr0 = r0 - rs;
  const int tid = threadIdx.x;
  const int lm = tid & 63, lk4 = tid >> 6;
  const int tx = tid & 15, ty = tid >> 4;
  float acc[4][4];
#pragma unroll
  for (int i = 0; i < 4; ++i)
#pragma unroll
    for (int q = 0; q < 4; ++q) acc[i][q] = 0.f;

  for (int kb = 0; kb < 512; kb += 32) {
    const float4 a0 = *(const float4*)(X + (size_t)(n0+lm)*512 + kb + lk4*8);
    const float4 a1 = *(const float4*)(X + (size_t)(n0+lm)*512 + kb + lk4*8 + 4);
    const float4 c0 = *(const float4*)(W + (size_t)(lr0+lm)*512 + kb + lk4*8);
    const float4 c1 = *(const float4*)(W + (size_t)(lr0+lm)*512 + kb + lk4*8 + 4);
    __syncthreads();
    At[(lk4*8+0)*64+lm]=a0.x; At[(lk4*8+1)*64+lm]=a0.y; At[(lk4*8+2)*64+lm]=a0.z; At[(lk4*8+3)*64+lm]=a0.w;
    At[(lk4*8+4)*64+lm]=a1.x; At[(lk4*8+5)*64+lm]=a1.y; At[(lk4*8+6)*64+lm]=a1.z; At[(lk4*8+7)*64+lm]=a1.w;
    Bt[(lk4*8+0)*64+lm]=c0.x; Bt[(lk4*8+1)*64+lm]=c0.y; Bt[(lk4*8+2)*64+lm]=c0.z; Bt[(lk4*8+3)*64+lm]=c0.w;
    Bt[(lk4*8+4)*64+lm]=c1.x; Bt[(lk4*8+5)*64+lm]=c1.y; Bt[(lk4*8+6)*64+lm]=c1.z; Bt[(lk4*8+7)*64+lm]=c1.w;
    __syncthreads();
#pragma unroll
    for (int k = 0; k < 32; ++k) {
      const float4 av = *(const float4*)&At[k*64 + ty*4];
      const float4 bv = *(const float4*)&Bt[k*64 + tx*4];
      acc[0][0]=fmaf(av.x,bv.x,acc[0][0]); acc[0][1]=fmaf(av.x,bv.y,acc[0][1]); acc[0][2]=fmaf(av.x,bv.z,acc[0][2]); acc[0][3]=fmaf(av.x,bv.w,acc[0][3]);
      acc[1][0]=fmaf(av.y,bv.x,acc[1][0]); acc[1][1]=fmaf(av.y,bv.y,acc[1][1]); acc[1][2]=fmaf(av.y,bv.z,acc[1][2]); acc[1][3]=fmaf(av.y,bv.w,acc[1][3]);
      acc[2][0]=fmaf(av.z,bv.x,acc[2][0]); acc[2][1]=fmaf(av.z,bv.y,acc[2][1]); acc[2][2]=fmaf(av.z,bv.z,acc[2][2]); acc[2][3]=fmaf(av.z,bv.w,acc[2][3]);
      acc[3][0]=fmaf(av.w,bv.x,acc[3][0]); acc[3][1]=fmaf(av.w,bv.y,acc[3][1]); acc[3][2]=fmaf(av.w,bv.z,acc[3][2]); acc[3][3]=fmaf(av.w,bv.w,acc[3][3]);
    }
  }
  const float4 bb = *(const float4*)(bias + lr0 + tx*4);
#pragma unroll
  for (int i = 0; i < 4; ++i) {
    float4 o;
    o.x = acc[i][0] + bb.x; o.y = acc[i][1] + bb.y; o.z = acc[i][2] + bb.z; o.w = acc[i][3] + bb.w;
    *(float4*)(GI + (size_t)(n0+ty*4+i)*RTOT + r0 + tx*4) = o;
  }
}

// ================= phase 2: persistent scans =================
struct ScanArgs {
  const float* GI;
  const float* rwhh; const float* rbhh; float* hs;  float* ringR; unsigned* fR;
  const float* w1;   const float* b1;   float* ha1;
  const float* w2;   const float* b2;   float* ha2; float* ring2; unsigned* f2;
  const float* w3;   const float* b3;   float* ha3; float* ring3; unsigned* f3;
  int* cnt;
};

// Expert scan (E3/E2): NWG WGs x 1024 on one XCD; OPW=32 outputs/WG; KCN=32
// lanes/output (in-wave reduce). Exchange = plain 4-slot L2 ring gated by
// per-WG flags (one shared 64B line): store -> __syncthreads (drains each
// wave's own vmcnt) -> tid0 relaxed-agent flag store. Consumer: poll flags
// (one line), acquire fence (L1 inv), plain vector loads.
template<int H, int NWG>
__device__ void expert_scan(const float* __restrict__ GIe, const float* __restrict__ whh,
                            const float* __restrict__ bhh, float* __restrict__ hall,
                            float* __restrict__ ring, unsigned* __restrict__ flags, int wg)
{
  constexpr int OPW = 32, KCN = 32;
  constexpr int CH = H / KCN;              // 16 (E3) / 8 (E2)
  constexpr int CF4 = CH / 4;
  const int tid = threadIdx.x;
  const int l = tid & 63;
  const int j = tid >> 5, kc = tid & 31;
  const int jg = wg * OPW + j;
  const int gbase = l & ~31;

  float4 wr[CF4], wz[CF4], wn[CF4];
#pragma unroll
  for (int i4 = 0; i4 < CF4; ++i4) {
    const int kk = kc * CH + i4 * 4;
    wr[i4] = *(const float4*)(whh + (size_t)jg * H + kk);
    wz[i4] = *(const float4*)(whh + (size_t)(H + jg) * H + kk);
    wn[i4] = *(const float4*)(whh + (size_t)(2 * H + jg) * H + kk);
  }
  const float gbr = bhh[jg], gbz = bhh[H + jg], gbn = bhh[2 * H + jg];
  // gi rotation: lane kc holds gi for steps t == kc (mod 32)
  float pgr, pgz, pgn;
  { const float* g = GIe + (size_t)kc * RTOT;
    pgr = g[jg]; pgz = g[H + jg]; pgn = g[2 * H + jg]; }

  for (int t = 0; t < NTOK; ++t) {
    const int sl = t & 31;
    const float gr = __shfl(pgr, gbase + sl);
    const float gz = __shfl(pgz, gbase + sl);
    const float gn = __shfl(pgn, gbase + sl);
    if (kc == sl && t + 32 < NTOK) {
      const float* g = GIe + (size_t)(t + 32) * RTOT;
      pgr = g[jg]; pgz = g[H + jg]; pgn = g[2 * H + jg];
    }
    float pr = 0.f, pz = 0.f, pn = 0.f, hprev = 0.f;
    if (t > 0) {
      const unsigned tg = (unsigned)t;
      unsigned f = __hip_atomic_load(flags + (l & (NWG - 1)), __ATOMIC_RELAXED,
                                     __HIP_MEMORY_SCOPE_AGENT);
      while (!__all(f >= tg))
        f = __hip_atomic_load(flags + (l & (NWG - 1)), __ATOMIC_RELAXED,
                              __HIP_MEMORY_SCOPE_AGENT);
      __builtin_amdgcn_fence(__ATOMIC_ACQUIRE, "agent");
      const float* base = ring + (size_t)((t - 1) & 3) * H;
      hprev = base[jg];
#pragma unroll
      for (int i4 = 0; i4 < CF4; ++i4) {
        const float4 h4 = *(const float4*)(base + kc * CH + i4 * 4);
        pr = fmaf(wr[i4].x, h4.x, pr); pr = fmaf(wr[i4].y, h4.y, pr);
        pr = fmaf(wr[i4].z, h4.z, pr); pr = fmaf(wr[i4].w, h4.w, pr);
        pz = fmaf(wz[i4].x, h4.x, pz); pz = fmaf(wz[i4].y, h4.y, pz);
        pz = fmaf(wz[i4].z, h4.z, pz); pz = fmaf(wz[i4].w, h4.w, pz);
        pn = fmaf(wn[i4].x, h4.x, pn); pn = fmaf(wn[i4].y, h4.y, pn);
        pn = fmaf(wn[i4].z, h4.z, pn); pn = fmaf(wn[i4].w, h4.w, pn);
      }
#pragma unroll
      for (int off = 16; off; off >>= 1) {
        pr += __shfl_xor(pr, off); pz += __shfl_xor(pz, off); pn += __shfl_xor(pn, off);
      }
    }
    const float rg = sigm(gr + gbr + pr);
    const float zg = sigm(gz + gbz + pz);
    const float nn = tanhf(gn + rg * (pn + gbn));
    const float hn = (1.f - zg) * nn + zg * hprev;
    if (kc == 0) {
      ring[(size_t)(t & 3) * H + jg] = hn;
      hall[(size_t)t * H + jg] = hn;       // history, off-chain (drains next sync)
    }
    __syncthreads();                        // each wave drains own vmcnt, then barrier
    if (tid == 0)
      __hip_atomic_store(flags + wg, (unsigned)(t + 1), __ATOMIC_RELAXED,
                         __HIP_MEMORY_SCOPE_AGENT);
  }
}

// Router scan: 16 WGs x 1024. Wave = output j; lane = (bg in [0,4), kc in [0,16));
// each lane covers 4 batch rows, k-chunk 16.
__device__ void router_scan(const float* __restrict__ GI, const float* __restrict__ whh,
                            const float* __restrict__ bhh, float* __restrict__ hs,
                            float* __restrict__ ring, unsigned* __restrict__ flags, int wg)
{
  const int tid = threadIdx.x;
  const int l = tid & 63;
  const int j = tid >> 6;
  const int bg = (l >> 4) & 3;
  const int kc = l & 15;
  const int jg = wg * 16 + j;
  float4 wr[4], wz[4], wn[4];
#pragma unroll
  for (int i4 = 0; i4 < 4; ++i4) {
    const int kk = kc * 16 + i4 * 4;
    wr[i4] = *(const float4*)(whh + (size_t)jg * 256 + kk);
    wz[i4] = *(const float4*)(whh + (size_t)(256 + jg) * 256 + kk);
    wn[i4] = *(const float4*)(whh + (size_t)(512 + jg) * 256 + kk);
  }
  const float gbr = bhh[jg], gbz = bhh[256 + jg], gbn = bhh[512 + jg];
  float pg[12];                            // gi rotation: lane kc holds t == kc (mod 16)
#pragma unroll
  for (int i = 0; i < 4; ++i) {
    const float* g = GI + (size_t)(kc * 16 + bg * 4 + i) * RTOT;
    pg[i*3+0] = g[jg]; pg[i*3+1] = g[256 + jg]; pg[i*3+2] = g[512 + jg];
  }
  for (int t = 0; t < TT; ++t) {
    const int sl = t & 15;
    const int src = (l & 48) + sl;
    float gr[4], gz[4], gn[4];
#pragma unroll
    for (int i = 0; i < 4; ++i) {
      gr[i] = __shfl(pg[i*3+0], src);
      gz[i] = __shfl(pg[i*3+1], src);
      gn[i] = __shfl(pg[i*3+2], src);
    }
    if (kc == sl && t + 16 < TT) {
#pragma unroll
      for (int i = 0; i < 4; ++i) {
        const float* g = GI + (size_t)((t + 16) * 16 + bg * 4 + i) * RTOT;
        pg[i*3+0] = g[jg]; pg[i*3+1] = g[256 + jg]; pg[i*3+2] = g[512 + jg];
      }
    }
    float ar[4] = {0,0,0,0}, az[4] = {0,0,0,0}, an[4] = {0,0,0,0}, hp[4] = {0,0,0,0};
    if (t > 0) {
      const unsigned tg = (unsigned)t;
      unsigned f = __hip_atomic_load(flags + (l & 15), __ATOMIC_RELAXED,
                                     __HIP_MEMORY_SCOPE_AGENT);
      while (!__all(f >= tg))
        f = __hip_atomic_load(flags + (l & 15), __ATOMIC_RELAXED,
                              __HIP_MEMORY_SCOPE_AGENT);
      __builtin_amdgcn_fence(__ATOMIC_ACQUIRE, "agent");
      const float* base = ring + (size_t)((t - 1) & 3) * 4096;
#pragma unroll
      for (int i = 0; i < 4; ++i) {
        const int b = bg * 4 + i;
        hp[i] = base[b * 256 + jg];
#pragma unroll
        for (int i4 = 0; i4 < 4; ++i4) {
          const float4 h4 = *(const float4*)(base + b * 256 + kc * 16 + i4 * 4);
          ar[i] = fmaf(wr[i4].x, h4.x, ar[i]); ar[i] = fmaf(wr[i4].y, h4.y, ar[i]);
          ar[i] = fmaf(wr[i4].z, h4.z, ar[i]); ar[i] = fmaf(wr[i4].w, h4.w, ar[i]);
          az[i] = fmaf(wz[i4].x, h4.x, az[i]); az[i] = fmaf(wz[i4].y, h4.y, az[i]);
          az[i] = fmaf(wz[i4].z, h4.z, az[i]); az[i] = fmaf(wz[i4].w, h4.w, az[i]);
          an[i] = fmaf(wn[i4].x, h4.x, an[i]); an[i] = fmaf(wn[i4].y, h4.y, an[i]);
          an[i] = fmaf(wn[i4].z, h4.z, an[i]); an[i] = fmaf(wn[i4].w, h4.w, an[i]);
        }
      }
#pragma unroll
      for (int off = 8; off; off >>= 1) {
#pragma unroll
        for (int i = 0; i < 4; ++i) {
          ar[i] += __shfl_xor(ar[i], off);
          az[i] += __shfl_xor(az[i], off);
          an[i] += __shfl_xor(an[i], off);
        }
      }
    }
#pragma unroll
    for (int i = 0; i < 4; ++i) {
      const float rg = sigm(gr[i] + gbr + ar[i]);
      const float zg = sigm(gz[i] + gbz + az[i]);
      const float nn = tanhf(gn[i] + rg * (an[i] + gbn));
      const float hn = (1.f - zg) * nn + zg * hp[i];
      if (kc == 0) {
        const int b = bg * 4 + i;
        ring[(size_t)(t & 3) * 4096 + b * 256 + jg] = hn;
        hs[(size_t)t * 4096 + b * 256 + jg] = hn;
      }
    }
    __syncthreads();
    if (tid == 0)
      __hip_atomic_store(flags + wg, (unsigned)(t + 1), __ATOMIC_RELAXED,
                         __HIP_MEMORY_SCOPE_AGENT);
  }
}

// E1: single WG x 1024, LDS exchange with per-wave LDS flags (no barriers).
// j = tid>>3 in [0,128), kc = tid&7, chunk 16.
__device__ void e1_scan(const float* __restrict__ GIe, const float* __restrict__ whh,
                        const float* __restrict__ bhh, float* __restrict__ hall,
                        float* __restrict__ sm)
{
  volatile float* vh = sm;                 // [0,256): h dbuf
  volatile int* wf = (volatile int*)(sm + 256);   // [256,272): 16 wave flags
  const int tid = threadIdx.x;
  const int l = tid & 63, w = tid >> 6;
  const int j = tid >> 3, kc = tid & 7;
  const int gbase = l & ~7;
  if (tid < 16) wf[tid] = 0;
  float4 wr[4], wz[4], wn[4];
#pragma unroll
  for (int i4 = 0; i4 < 4; ++i4) {
    const int kk = kc * 16 + i4 * 4;
    wr[i4] = *(const float4*)(whh + (size_t)j * 128 + kk);
    wz[i4] = *(const float4*)(whh + (size_t)(128 + j) * 128 + kk);
    wn[i4] = *(const float4*)(whh + (size_t)(256 + j) * 128 + kk);
  }
  const float gbr = bhh[j], gbz = bhh[128 + j], gbn = bhh[256 + j];
  float pgr, pgz, pgn;
  { const float* g = GIe + (size_t)kc * RTOT;
    pgr = g[j]; pgz = g[128 + j]; pgn = g[256 + j]; }
  __syncthreads();                          // flags zeroed

  for (int t = 0; t < NTOK; ++t) {
    const int sl = t & 7;
    const float gr = __shfl(pgr, gbase + sl);
    const float gz = __shfl(pgz, gbase + sl);
    const float gn = __shfl(pgn, gbase + sl);
    if (kc == sl && t + 8 < NTOK) {
      const float* g = GIe + (size_t)(t + 8) * RTOT;
      pgr = g[j]; pgz = g[128 + j]; pgn = g[256 + j];
    }
    float pr = 0.f, pz = 0.f, pn = 0.f, hprev = 0.f;
    if (t > 0) {
      int v = wf[l & 15];
      while (!__all(v >= t)) v = wf[l & 15];
      __builtin_amdgcn_fence(__ATOMIC_ACQUIRE, "workgroup");
      const float* base = sm + ((t - 1) & 1) * 128;
      hprev = base[j];
#pragma unroll
      for (int i4 = 0; i4 < 4; ++i4) {
        const float4 h4 = *(const float4*)(base + kc * 16 + i4 * 4);
        pr = fmaf(wr[i4].x, h4.x, pr); pr = fmaf(wr[i4].y, h4.y, pr);
        pr = fmaf(wr[i4].z, h4.z, pr); pr = fmaf(wr[i4].w, h4.w, pr);
        pz = fmaf(wz[i4].x, h4.x, pz); pz = fmaf(wz[i4].y, h4.y, pz);
        pz = fmaf(wz[i4].z, h4.z, pz); pz = fmaf(wz[i4].w, h4.w, pz);
        pn = fmaf(wn[i4].x, h4.x, pn); pn = fmaf(wn[i4].y, h4.y, pn);
        pn = fmaf(wn[i4].z, h4.z, pn); pn = fmaf(wn[i4].w, h4.w, pn);
      }
#pragma unroll
      for (int off = 4; off; off >>= 1) {
        pr += __shfl_xor(pr, off); pz += __shfl_xor(pz, off); pn += __shfl_xor(pn, off);
      }
    }
    const float rg = sigm(gr + gbr + pr);
    const float zg = sigm(gz + gbz + pz);
    const float nn = tanhf(gn + rg * (pn + gbn));
    const float hn = (1.f - zg) * nn + zg * hprev;
    if (kc == 0) {
      vh[(t & 1) * 128 + j] = hn;           // volatile ds_write (ordered before flag)
      hall[(size_t)t * 128 + j] = hn;
    }
    if (l == 0) wf[w] = t + 1;              // same-wave in-order LDS publish
  }
}

__global__ __launch_bounds__(1024, 1) void scan_kernel(ScanArgs A)
{
  // 84 KiB LDS: occupancy blocker (2 WGs would need 168 KiB > 160) + E1 exchange.
  // Dynamically indexed (E1 + claim probe) so the compiler cannot shrink it.
  __shared__ float sm[21504];
  __shared__ int role_s[2];
  if (threadIdx.x == 0) {
    unsigned x;
    asm volatile("s_getreg_b32 %0, hwreg(HW_REG_XCC_ID)" : "=s"(x));
    const int xcd = (int)(x & 7u);
    role_s[0] = xcd;
    const int r = atomicAdd(A.cnt + xcd, 1);
    role_s[1] = r;
    ((volatile float*)sm)[(r * 97 + xcd * 13) % 21504] = 0.f;  // keep full LDS alloc
  }
  __syncthreads();
  const int xcd = role_s[0], r = role_s[1];
  if (xcd == 0)      { if (r < 16) expert_scan<512, 16>(A.GI + E3OFF, A.w3, A.b3, A.ha3, A.ring3, A.f3, r); }
  else if (xcd == 1) { if (r < 16) router_scan(A.GI, A.rwhh, A.rbhh, A.hs, A.ringR, A.fR, r); }
  else if (xcd == 2) { if (r < 8)  expert_scan<256, 8>(A.GI + E2OFF, A.w2, A.b2, A.ha2, A.ring2, A.f2, r); }
  else if (xcd == 3) { if (r < 1)  e1_scan(A.GI + E1OFF, A.w1, A.b1, A.ha1, sm); }
}

// ================= phase 3a: router head, softmax, eul/task atomics =================
__global__ __launch_bounds__(256) void router_out_kernel(
    const float* __restrict__ hs, const float* __restrict__ ow, const float* __restrict__ ob,
    const int* __restrict__ tids, float* __restrict__ raw_out,
    float* __restrict__ tsum, float* __restrict__ tcnt)
{
  const int tid = threadIdx.x;
  const int lane = tid & 63, w = tid >> 6;
  const int n = blockIdx.x * 4 + w;
  float s0 = 0.f, s1 = 0.f, s2 = 0.f, s3 = 0.f;
#pragma unroll
  for (int q = 0; q < 4; ++q) {
    const int jj = lane + q * 64;
    float h = hs[(size_t)n * 256 + jj];
    h = h > 0.f ? h : 0.f;
    s0 = fmaf(h, ow[jj], s0);
    s1 = fmaf(h, ow[256 + jj], s1);
    s2 = fmaf(h, ow[512 + jj], s2);
    s3 = fmaf(h, ow[768 + jj], s3);
  }
  for (int off = 32; off; off >>= 1) {
    s0 += __shfl_xor(s0, off); s1 += __shfl_xor(s1, off);
    s2 += __shfl_xor(s2, off); s3 += __shfl_xor(s3, off);
  }
  if (lane == 0) {
    const float l0 = s0 + ob[0], l1 = s1 + ob[1], l2 = s2 + ob[2], l3 = s3 + ob[3];
    const float m = fmaxf(fmaxf(l0, l1), fmaxf(l2, l3));
    const float e0 = expf(l0 - m), e1 = expf(l1 - m), e2 = expf(l2 - m), e3 = expf(l3 - m);
    const float inv = 1.f / (e0 + e1 + e2 + e3);
    float4 rv; rv.x = e0 * inv; rv.y = e1 * inv; rv.z = e2 * inv; rv.w = e3 * inv;
    *(float4*)(raw_out + (size_t)n * 4) = rv;
    const float eul = rv.y * 128.f + rv.z * 256.f + rv.w * 512.f;
    const int tk = tids[n];
    atomicAdd(&tsum[tk], eul);
    atomicAdd(&tcnt[tk], 1.f);
  }
}

// ================= phase 3b: BN stats per column =================
__global__ __launch_bounds__(256) void bn_stats_kernel(
    const float* __restrict__ h1, const float* __restrict__ h2, const float* __restrict__ h3,
    float* __restrict__ mu, float* __restrict__ rstd)
{
  const int c = blockIdx.x;
  const float* hp; int He, hc;
  if (c < 128)      { hp = h1; He = 128; hc = c; }
  else if (c < 384) { hp = h2; He = 256; hc = c - 128; }
  else              { hp = h3; He = 512; hc = c - 384; }
  float s = 0.f, s2 = 0.f;
  for (int r = threadIdx.x; r < NTOK; r += 256) {
    const float v = hp[(size_t)r * He + hc];
    s += v; s2 = fmaf(v, v, s2);
  }
  for (int off = 32; off; off >>= 1) { s += __shfl_xor(s, off); s2 += __shfl_xor(s2, off); }
  __shared__ float red[8];
  const int lane = threadIdx.x & 63, w = threadIdx.x >> 6;
  if (lane == 0) { red[w] = s; red[4 + w] = s2; }
  __syncthreads();
  if (threadIdx.x == 0) {
    const float S = red[0] + red[1] + red[2] + red[3];
    const float S2 = red[4] + red[5] + red[6] + red[7];
    const float m = S * (1.f / 4096.f);
    float v = S2 * (1.f / 4096.f) - m * m;
    v = v > 0.f ? v : 0.f;
    mu[c] = m;
    rstd[c] = 1.f / sqrtf(v + 1e-5f);
  }
}

// ================= phase 3c: A' = gate * relu(bn(h)); plus task losses =================
__global__ __launch_bounds__(256) void aprime_kernel(
    const float* __restrict__ h1, const float* __restrict__ h2, const float* __restrict__ h3,
    const float* __restrict__ g1, const float* __restrict__ be1,
    const float* __restrict__ g2, const float* __restrict__ be2,
    const float* __restrict__ g3, const float* __restrict__ be3,
    const float* __restrict__ mu, const float* __restrict__ rstd,
    const float* __restrict__ raw, float* __restrict__ Ap,
    const float* __restrict__ tsum, const float* __restrict__ tcnt, float* __restrict__ tl_out)
{
  if (blockIdx.x == 4096) {
    if (threadIdx.x < 4) tl_out[threadIdx.x] = tsum[threadIdx.x] / tcnt[threadIdx.x];
    return;
  }
  const int n = blockIdx.x;
  for (int c = threadIdx.x; c < 896; c += 256) {
    const float* hp; const float* gg; const float* bb; int He, hc, e;
    if (c < 128)      { hp = h1; gg = g1; bb = be1; He = 128; hc = c;       e = 1; }
    else if (c < 384) { hp = h2; gg = g2; bb = be2; He = 256; hc = c - 128; e = 2; }
    else              { hp = h3; gg = g3; bb = be3; He = 512; hc = c - 384; e = 3; }
    const float h = hp[(size_t)n * He + hc];
    float v = (h - mu[c]) * rstd[c] * gg[hc] + bb[hc];
    v = v > 0.f ? v : 0.f;
    Ap[(size_t)n * 896 + c] = raw[(size_t)n * 4 + e] * v;
  }
}

// ================= phase 4: out = A' @ OWc^T + gated biases + g0*x =================
__global__ __launch_bounds__(256) void out_gemm_kernel(
    const float* __restrict__ Ap,
    const float* __restrict__ ow1, const float* __restrict__ ow2, const float* __restrict__ ow3,
    const float* __restrict__ ob1, const float* __restrict__ ob2, const float* __restrict__ ob3,
    const float* __restrict__ X, const float* __restrict__ raw, float* __restrict__ out)
{
  __shared__ float At[32*64];
  __shared__ float Bt[32*64];
  const int n0 = blockIdx.x * 64;
  const int d0 = blockIdx.y * 64;
  const int tid = threadIdx.x;
  const int lm = tid & 63, lk4 = tid >> 6;
  const int tx = tid & 15, ty = tid >> 4;
  float acc[4][4];
#pragma unroll
  for (int i = 0; i < 4; ++i)
#pragma unroll
    for (int q = 0; q < 4; ++q) acc[i][q] = 0.f;

  for (int kb = 0; kb < 896; kb += 32) {
    const float* W; int He, ko;
    if (kb < 128)      { W = ow1; He = 128; ko = 0; }
    else if (kb < 384) { W = ow2; He = 256; ko = 128; }
    else               { W = ow3; He = 512; ko = 384; }
    const float4 a0 = *(const float4*)(Ap + (size_t)(n0+lm)*896 + kb + lk4*8);
    const float4 a1 = *(const float4*)(Ap + (size_t)(n0+lm)*896 + kb + lk4*8 + 4);
    const float4 c0 = *(const float4*)(W + (size_t)(d0+lm)*He + (kb - ko) + lk4*8);
    const float4 c1 = *(const float4*)(W + (size_t)(d0+lm)*He + (kb - ko) + lk4*8 + 4);
    __syncthreads();
    At[(lk4*8+0)*64+lm]=a0.x; At[(lk4*8+1)*64+lm]=a0.y; At[(lk4*8+2)*64+lm]=a0.z; At[(lk4*8+3)*64+lm]=a0.w;
    At[(lk4*8+4)*64+lm]=a1.x; At[(lk4*8+5)*64+lm]=a1.y; At[(lk4*8+6)*64+lm]=a1.z; At[(lk4*8+7)*64+lm]=a1.w;
    Bt[(lk4*8+0)*64+lm]=c0.x; Bt[(lk4*8+1)*64+lm]=c0.y; Bt[(lk4*8+2)*64+lm]=c0.z; Bt[(lk4*8+3)*64+lm]=c0.w;
    Bt[(lk4*8+4)*64+lm]=c1.x; Bt[(lk4*8+5)*64+lm]=c1.y; Bt[(lk4*8+6)*64+lm]=c1.z; Bt[(lk4*8+7)*64+lm]=c1.w;
    __syncthreads();
#pragma unroll
    for (int k = 0; k < 32; ++k) {
      const float4 av = *(const float4*)&At[k*64 + ty*4];
      const float4 bv = *(const float4*)&Bt[k*64 + tx*4];
      acc[0][0]=fmaf(av.x,bv.x,acc[0][0]); acc[0][1]=fmaf(av.x,bv.y,acc[0][1]); acc[0][2]=fmaf(av.x,bv.z,acc[0][2]); acc[0][3]=fmaf(av.x,bv.w,acc[0][3]);
      acc[1][0]=fmaf(av.y,bv.x,acc[1][0]); acc[1][1]=fmaf(av.y,bv.y,acc[1][1]); acc[1][2]=fmaf(av.y,bv.z,acc[1][2]); acc[1][3]=fmaf(av.y,bv.w,acc[1][3]);
      acc[2][0]=fmaf(av.z,bv.x,acc[2][0]); acc[2][1]=fmaf(av.z,bv.y,acc[2][1]); acc[2][2]=fmaf(av.z,bv.z,acc[2][2]); acc[2][3]=fmaf(av.z,bv.w,acc[2][3]);
      acc[3][0]=fmaf(av.w,bv.x,acc[3][0]); acc[3][1]=fmaf(av.w,bv.y,acc[3][1]); acc[3][2]=fmaf(av.w,bv.z,acc[3][2]); acc[3][3]=fmaf(av.w,bv.w,acc[3][3]);
    }
  }
#pragma unroll
  for (int i = 0; i < 4; ++i) {
    const int n = n0 + ty * 4 + i;
    const float4 g  = *(const float4*)(raw + (size_t)n * 4);
    const float4 xv = *(const float4*)(X + (size_t)n * 512 + d0 + tx * 4);
    const float4 o1 = *(const float4*)(ob1 + d0 + tx * 4);
    const float4 o2 = *(const float4*)(ob2 + d0 + tx * 4);
    const float4 o3 = *(const float4*)(ob3 + d0 + tx * 4);
    float4 o;
    o.x = acc[i][0] + g.x*xv.x + g.y*o1.x + g.z*o2.x + g.w*o3.x;
    o.y = acc[i][1] + g.x*xv.y + g.y*o1.y + g.z*o2.y + g.w*o3.y;
    o.z = acc[i][2] + g.x*xv.z + g.y*o1.z + g.z*o2.z + g.w*o3.z;
    o.w = acc[i][3] + g.x*xv.w + g.y*o1.w + g.z*o2.w + g.w*o3.w;
    *(float4*)(out + (size_t)n * 512 + d0 + tx * 4) = o;
  }
}

// ================= host =================
extern "C" void kernel_launch(void* const* d_in, const int* in_sizes, int n_in,
                              void* d_out, int out_size, void* d_ws, size_t ws_size,
                              hipStream_t stream) {
  const float* x    = (const float*)d_in[0];
  const int*   tids = (const int*)d_in[1];
  const float* rwih = (const float*)d_in[2];
  const float* rwhh = (const float*)d_in[3];
  const float* rbih = (const float*)d_in[4];
  const float* rbhh = (const float*)d_in[5];
  const float* row  = (const float*)d_in[6];
  const float* rob  = (const float*)d_in[7];
  const float* w1ih = (const float*)d_in[8];
  const float* w1hh = (const float*)d_in[9];
  const float* b1ih = (const float*)d_in[10];
  const float* b1hh = (const float*)d_in[11];
  const float* bn1g = (const float*)d_in[12];
  const float* bn1b = (const float*)d_in[13];
  const float* ow1  = (const float*)d_in[14];
  const float* ob1  = (const float*)d_in[15];
  const float* w2ih = (const float*)d_in[16];
  const float* w2hh = (const float*)d_in[17];
  const float* b2ih = (const float*)d_in[18];
  const float* b2hh = (const float*)d_in[19];
  const float* bn2g = (const float*)d_in[20];
  const float* bn2b = (const float*)d_in[21];
  const float* ow2  = (const float*)d_in[22];
  const float* ob2  = (const float*)d_in[23];
  const float* w3ih = (const float*)d_in[24];
  const float* w3hh = (const float*)d_in[25];
  const float* b3ih = (const float*)d_in[26];
  const float* b3hh = (const float*)d_in[27];
  const float* bn3g = (const float*)d_in[28];
  const float* bn3b = (const float*)d_in[29];
  const float* ow3  = (const float*)d_in[30];
  const float* ob3  = (const float*)d_in[31];

  char* ws = (char*)d_ws;
  float*    tsum  = (float*)(ws + OFF_TSUM);
  float*    tcnt  = (float*)(ws + OFF_TCNT);
  int*      cnt   = (int*)(ws + OFF_CNT);
  unsigned* fR    = (unsigned*)(ws + OFF_FR);
  unsigned* f3    = (unsigned*)(ws + OFF_F3);
  unsigned* f2    = (unsigned*)(ws + OFF_F2);
  float*    ringR = (float*)(ws + OFF_RINGR);
  float*    ring3 = (float*)(ws + OFF_RING3);
  float*    ring2 = (float*)(ws + OFF_RING2);
  float*    GI    = (float*)(ws + OFF_GI);
  float*    hs    = (float*)(ws + OFF_HS);
  float*    ha3   = (float*)(ws + OFF_HA3);
  float*    ha2   = (float*)(ws + OFF_HA2);
  float*    ha1   = (float*)(ws + OFF_HA1);
  float*    Ap    = (float*)(ws + OFF_AP);
  float*    mu    = (float*)(ws + OFF_MU);
  float*    rstd  = (float*)(ws + OFF_RSTD);

  float* outp = (float*)d_out;
  float* rawp = outp + (size_t)NTOK * DD;
  float* tlp  = rawp + (size_t)NTOK * 4;

  // zero claim counters, task accumulators, and ALL publish flags
  hipMemsetAsync(ws, 0, ZBYTES, stream);

  // phase 1: input projections for router + all experts
  gemm1_kernel<<<dim3(64, 54), 256, 0, stream>>>(x, rwih, w1ih, w2ih, w3ih,
                                                 rbih, b1ih, b2ih, b3ih, GI);

  // phase 2: XCD-claimed scans; flag-gated L2 rings; 84KB LDS => 1 WG/CU
  ScanArgs sa;
  sa.GI = GI;
  sa.rwhh = rwhh; sa.rbhh = rbhh; sa.hs = hs;  sa.ringR = ringR; sa.fR = fR;
  sa.w1 = w1hh;   sa.b1 = b1hh;   sa.ha1 = ha1;
  sa.w2 = w2hh;   sa.b2 = b2hh;   sa.ha2 = ha2; sa.ring2 = ring2; sa.f2 = f2;
  sa.w3 = w3hh;   sa.b3 = b3hh;   sa.ha3 = ha3; sa.ring3 = ring3; sa.f3 = f3;
  sa.cnt = cnt;
  scan_kernel<<<dim3(512), dim3(1024), 0, stream>>>(sa);

  // phase 3: router head + task-loss atomics; BN stats; A' build (+ task losses)
  router_out_kernel<<<dim3(1024), 256, 0, stream>>>(hs, row, rob, tids, rawp, tsum, tcnt);
  bn_stats_kernel<<<dim3(896), 256, 0, stream>>>(ha1, ha2, ha3, mu, rstd);
  aprime_kernel<<<dim3(4097), 256, 0, stream>>>(ha1, ha2, ha3, bn1g, bn1b, bn2g, bn2b,
                                                bn3g, bn3b, mu, rstd, rawp, Ap,
                                                tsum, tcnt, tlp);

  // phase 4: gated expert-output GEMM + identity expert + gated biases
  out_gemm_kernel<<<dim3(64, 8), 256, 0, stream>>>(Ap, ow1, ow2, ow3, ob1, ob2, ob3,
                                                   x, rawp, outp);
}

// Round 7
// 19144.226 us; speedup vs baseline: 3.8989x; 3.8989x over previous
//
#include <hip/hip_runtime.h>
#include <math.h>

// ---------------- problem constants ----------------
constexpr int TT = 256, BB = 16, DD = 512;
constexpr int NTOK = 4096;                 // T*B
constexpr int RTOT = 3456;                 // 768 + 384 + 768 + 1536
constexpr int E1OFF = 768, E2OFF = 1152, E3OFF = 1920;

typedef unsigned long long ull;

// ---------------- workspace layout (bytes) ----------------
constexpr size_t OFF_TSUM  = 0;                                  // 4 f
constexpr size_t OFF_TCNT  = 16;                                 // 4 f
constexpr size_t OFF_CNT   = 32;                                 // 8 ints (XCD claim)
constexpr size_t OFF_F3    = 1024;                               // 128 u32 (E3 wave flags)
constexpr size_t OFF_FR    = 1536;                               // 128 u32 (router wave flags)
constexpr size_t OFF_F2    = 2048;                               // 64 u32 (E2 wave flags)
constexpr size_t ZBYTES    = 4096;                               // memset-0 range
constexpr size_t OFF_RING3 = 4096;                               // 4*512*4  = 8 KB
constexpr size_t OFF_RING2 = OFF_RING3 + 4ull*512*4;             // 4*256*4  = 4 KB
constexpr size_t OFF_RINGR = OFF_RING2 + 4ull*256*4;             // 4*4096*4 = 64 KB
constexpr size_t OFF_GI   = 131072;
constexpr size_t OFF_HS   = OFF_GI  + (size_t)NTOK*RTOT*4;
constexpr size_t OFF_HA3  = OFF_HS  + (size_t)NTOK*256*4;
constexpr size_t OFF_HA2  = OFF_HA3 + (size_t)NTOK*512*4;
constexpr size_t OFF_HA1  = OFF_HA2 + (size_t)NTOK*256*4;
constexpr size_t OFF_AP   = OFF_HA1 + (size_t)NTOK*128*4;
constexpr size_t OFF_MU   = OFF_AP  + (size_t)NTOK*896*4;
constexpr size_t OFF_RSTD = OFF_MU  + 896*4;

__device__ __forceinline__ float sigm(float x) { return 1.f / (1.f + expf(-x)); }
__device__ __forceinline__ unsigned agld(const unsigned* p) {
  return __hip_atomic_load(p, __ATOMIC_RELAXED, __HIP_MEMORY_SCOPE_AGENT);
}
__device__ __forceinline__ ull agld8(const ull* p) {
  return __hip_atomic_load(p, __ATOMIC_RELAXED, __HIP_MEMORY_SCOPE_AGENT);
}
__device__ __forceinline__ void agstf(float* p, float v) {
  __hip_atomic_store(p, v, __ATOMIC_RELAXED, __HIP_MEMORY_SCOPE_AGENT);
}
__device__ __forceinline__ void agstu(unsigned* p, unsigned v) {
  __hip_atomic_store(p, v, __ATOMIC_RELAXED, __HIP_MEMORY_SCOPE_AGENT);
}

// ================= phase 1: gi = x @ Wih^T + b_ih (all 3456 rows) =================
__global__ __launch_bounds__(256) void gemm1_kernel(
    const float* __restrict__ X,
    const float* __restrict__ wR, const float* __restrict__ w1,
    const float* __restrict__ w2, const float* __restrict__ w3,
    const float* __restrict__ bR, const float* __restrict__ b1,
    const float* __restrict__ b2, const float* __restrict__ b3,
    float* __restrict__ GI)
{
  __shared__ float At[32*64];
  __shared__ float Bt[32*64];
  const int n0 = blockIdx.x * 64;
  const int r0 = blockIdx.y * 64;
  const float* W; const float* bias; int rs;
  if (r0 < 768)       { W = wR; bias = bR; rs = 0; }
  else if (r0 < 1152) { W = w1; bias = b1; rs = 768; }
  else if (r0 < 1920) { W = w2; bias = b2; rs = 1152; }
  else                { W = w3; bias = b3; rs = 1920; }
  const int lr0 = r0 - rs;
  const int tid = threadIdx.x;
  const int lm = tid & 63, lk4 = tid >> 6;
  const int tx = tid & 15, ty = tid >> 4;
  float acc[4][4];
#pragma unroll
  for (int i = 0; i < 4; ++i)
#pragma unroll
    for (int q = 0; q < 4; ++q) acc[i][q] = 0.f;

  for (int kb = 0; kb < 512; kb += 32) {
    const float4 a0 = *(const float4*)(X + (size_t)(n0+lm)*512 + kb + lk4*8);
    const float4 a1 = *(const float4*)(X + (size_t)(n0+lm)*512 + kb + lk4*8 + 4);
    const float4 c0 = *(const float4*)(W + (size_t)(lr0+lm)*512 + kb + lk4*8);
    const float4 c1 = *(const float4*)(W + (size_t)(lr0+lm)*512 + kb + lk4*8 + 4);
    __syncthreads();
    At[(lk4*8+0)*64+lm]=a0.x; At[(lk4*8+1)*64+lm]=a0.y; At[(lk4*8+2)*64+lm]=a0.z; At[(lk4*8+3)*64+lm]=a0.w;
    At[(lk4*8+4)*64+lm]=a1.x; At[(lk4*8+5)*64+lm]=a1.y; At[(lk4*8+6)*64+lm]=a1.z; At[(lk4*8+7)*64+lm]=a1.w;
    Bt[(lk4*8+0)*64+lm]=c0.x; Bt[(lk4*8+1)*64+lm]=c0.y; Bt[(lk4*8+2)*64+lm]=c0.z; Bt[(lk4*8+3)*64+lm]=c0.w;
    Bt[(lk4*8+4)*64+lm]=c1.x; Bt[(lk4*8+5)*64+lm]=c1.y; Bt[(lk4*8+6)*64+lm]=c1.z; Bt[(lk4*8+7)*64+lm]=c1.w;
    __syncthreads();
#pragma unroll
    for (int k = 0; k < 32; ++k) {
      const float4 av = *(const float4*)&At[k*64 + ty*4];
      const float4 bv = *(const float4*)&Bt[k*64 + tx*4];
      acc[0][0]=fmaf(av.x,bv.x,acc[0][0]); acc[0][1]=fmaf(av.x,bv.y,acc[0][1]); acc[0][2]=fmaf(av.x,bv.z,acc[0][2]); acc[0][3]=fmaf(av.x,bv.w,acc[0][3]);
      acc[1][0]=fmaf(av.y,bv.x,acc[1][0]); acc[1][1]=fmaf(av.y,bv.y,acc[1][1]); acc[1][2]=fmaf(av.y,bv.z,acc[1][2]); acc[1][3]=fmaf(av.y,bv.w,acc[1][3]);
      acc[2][0]=fmaf(av.z,bv.x,acc[2][0]); acc[2][1]=fmaf(av.z,bv.y,acc[2][1]); acc[2][2]=fmaf(av.z,bv.z,acc[2][2]); acc[2][3]=fmaf(av.z,bv.w,acc[2][3]);
      acc[3][0]=fmaf(av.w,bv.x,acc[3][0]); acc[3][1]=fmaf(av.w,bv.y,acc[3][1]); acc[3][2]=fmaf(av.w,bv.z,acc[3][2]); acc[3][3]=fmaf(av.w,bv.w,acc[3][3]);
    }
  }
  const float4 bb = *(const float4*)(bias + lr0 + tx*4);
#pragma unroll
  for (int i = 0; i < 4; ++i) {
    float4 o;
    o.x = acc[i][0] + bb.x; o.y = acc[i][1] + bb.y; o.z = acc[i][2] + bb.z; o.w = acc[i][3] + bb.w;
    *(float4*)(GI + (size_t)(n0+ty*4+i)*RTOT + r0 + tx*4) = o;
  }
}

// ================= phase 2: persistent scans =================
struct ScanArgs {
  const float* GI;
  const float* rwhh; const float* rbhh; float* hs;  float* ringR; unsigned* fR;
  const float* w1;   const float* b1;   float* ha1;
  const float* w2;   const float* b2;   float* ha2; float* ring2; unsigned* f2;
  const float* w3;   const float* b3;   float* ha3; float* ring3; unsigned* f3;
  int* cnt;
};

// Expert scan (E3: H=512,NWG=16 / E2: H=256,NWG=8). 512 thr, 32 outputs/WG,
// 16 lanes/output. Per-WAVE global flags; sc0 loads; no fences; wave0 polls
// + stages h into LDS dbuf; 1 barrier/step; gi batched every 16 steps.
template<int H, int NWG>
__device__ void expert_scan(const float* __restrict__ GIe, const float* __restrict__ whh,
                            const float* __restrict__ bhh, float* __restrict__ hall,
                            float* __restrict__ ring, unsigned* __restrict__ flags,
                            float* __restrict__ sm, int wg)
{
  constexpr int CH = H / 16, CF4 = CH / 4;
  constexpr int NFL = NWG * 8;
  const int tid = threadIdx.x;
  const int l = tid & 63, w = tid >> 6;
  const int j = tid >> 4, kc = tid & 15;
  const int jg = wg * 32 + j;

  float4 wr[CF4], wz[CF4], wn[CF4];
#pragma unroll
  for (int i4 = 0; i4 < CF4; ++i4) {
    const int kk = kc * CH + i4 * 4;
    wr[i4] = *(const float4*)(whh + (size_t)jg * H + kk);
    wz[i4] = *(const float4*)(whh + (size_t)(H + jg) * H + kk);
    wn[i4] = *(const float4*)(whh + (size_t)(2 * H + jg) * H + kk);
  }
  const float gbr = bhh[jg], gbz = bhh[H + jg], gbn = bhh[2 * H + jg];
  // gi rotation: lane kc holds gi for steps block+kc; refreshed once per 16 steps
  float pgr, pgz, pgn;
  { const float* g = GIe + (size_t)kc * RTOT;
    pgr = g[jg]; pgz = g[H + jg]; pgn = g[2 * H + jg]; }

  for (int t = 0; t < NTOK; ++t) {
    float* cur = sm + (size_t)(t & 1) * H;
    if (w == 0) {
      if (t > 0) {
        const unsigned tg = (unsigned)t;
        unsigned f0 = agld(flags + (l & (NFL - 1)));
        unsigned f1 = (NFL > 64) ? agld(flags + 64 + l) : tg;
        while (!__all(f0 >= tg && f1 >= tg)) {
          f0 = agld(flags + (l & (NFL - 1)));
          if (NFL > 64) f1 = agld(flags + 64 + l);
        }
        __asm__ __volatile__("" ::: "memory");
        if (l * 8 < H) {
          const ull* rp = (const ull*)(ring + (size_t)((t - 1) & 3) * H);
          const ull v0 = agld8(rp + l * 4 + 0);
          const ull v1 = agld8(rp + l * 4 + 1);
          const ull v2 = agld8(rp + l * 4 + 2);
          const ull v3 = agld8(rp + l * 4 + 3);
          *(float4*)(cur + l * 8) = make_float4(
              __uint_as_float((unsigned)v0), __uint_as_float((unsigned)(v0 >> 32)),
              __uint_as_float((unsigned)v1), __uint_as_float((unsigned)(v1 >> 32)));
          *(float4*)(cur + l * 8 + 4) = make_float4(
              __uint_as_float((unsigned)v2), __uint_as_float((unsigned)(v2 >> 32)),
              __uint_as_float((unsigned)v3), __uint_as_float((unsigned)(v3 >> 32)));
        }
      } else {
        if (l * 8 < H) {
          *(float4*)(cur + l * 8)     = make_float4(0.f, 0.f, 0.f, 0.f);
          *(float4*)(cur + l * 8 + 4) = make_float4(0.f, 0.f, 0.f, 0.f);
        }
      }
    }
    __syncthreads();                       // h_{t-1} staged (single barrier/step)
    const int sl = t & 15;
    const float gr = __shfl(pgr, (l & 48) + sl);
    const float gz = __shfl(pgz, (l & 48) + sl);
    const float gn = __shfl(pgn, (l & 48) + sl);
    float pr = 0.f, pz = 0.f, pn = 0.f;
#pragma unroll
    for (int i4 = 0; i4 < CF4; ++i4) {
      const float4 h4 = *(const float4*)(cur + kc * CH + i4 * 4);
      pr = fmaf(wr[i4].x, h4.x, pr); pr = fmaf(wr[i4].y, h4.y, pr);
      pr = fmaf(wr[i4].z, h4.z, pr); pr = fmaf(wr[i4].w, h4.w, pr);
      pz = fmaf(wz[i4].x, h4.x, pz); pz = fmaf(wz[i4].y, h4.y, pz);
      pz = fmaf(wz[i4].z, h4.z, pz); pz = fmaf(wz[i4].w, h4.w, pz);
      pn = fmaf(wn[i4].x, h4.x, pn); pn = fmaf(wn[i4].y, h4.y, pn);
      pn = fmaf(wn[i4].z, h4.z, pn); pn = fmaf(wn[i4].w, h4.w, pn);
    }
#pragma unroll
    for (int off = 8; off; off >>= 1) {
      pr += __shfl_down(pr, off); pz += __shfl_down(pz, off); pn += __shfl_down(pn, off);
    }
    if (kc == 0) {
      const float hprev = cur[jg];
      const float rg = sigm(gr + gbr + pr);
      const float zg = sigm(gz + gbz + pz);
      const float nn = tanhf(gn + rg * (pn + gbn));
      const float hn = (1.f - zg) * nn + zg * hprev;
      hall[(size_t)t * H + jg] = hn;                 // history (plain, L2-absorbed)
      agstf(ring + (size_t)(t & 3) * H + jg, hn);    // exchange (sc0)
    }
    __asm__ __volatile__("s_waitcnt vmcnt(0)" ::: "memory");  // wave's stores in L2
    if (l == 0) agstu(flags + wg * 8 + w, (unsigned)(t + 1));
    if (sl == 15 && t + 1 < NTOK) {                  // batch gi refresh (per 16 steps)
      int s = t + 1 + kc; if (s > NTOK - 1) s = NTOK - 1;
      const float* g = GIe + (size_t)s * RTOT;
      pgr = g[jg]; pgz = g[H + jg]; pgn = g[2 * H + jg];
    }
  }
}

// Router scan: 16 WGs x 512 on XCD1. lane=(j:16, bq:4, kc:8); 4 batches/lane.
__device__ void router_scan(const float* __restrict__ GI, const float* __restrict__ whh,
                            const float* __restrict__ bhh, float* __restrict__ hs,
                            float* __restrict__ ring, unsigned* __restrict__ flags,
                            float* __restrict__ sm, int wg)
{
  constexpr int RS = 264;                  // padded row stride (bank-spread across b)
  const int tid = threadIdx.x;
  const int l = tid & 63, w = tid >> 6;
  const int j = tid >> 5, r5 = tid & 31, bq = r5 >> 3, kc = r5 & 7;
  const int jg = wg * 16 + j;
  float4 wr[8], wz[8], wn[8];
#pragma unroll
  for (int i4 = 0; i4 < 8; ++i4) {
    const int kk = kc * 32 + i4 * 4;
    wr[i4] = *(const float4*)(whh + (size_t)jg * 256 + kk);
    wz[i4] = *(const float4*)(whh + (size_t)(256 + jg) * 256 + kk);
    wn[i4] = *(const float4*)(whh + (size_t)(512 + jg) * 256 + kk);
  }
  const float gbr = bhh[jg], gbz = bhh[256 + jg], gbn = bhh[512 + jg];
  float pg[12];                            // gi for 4 batches, steps block+kc
#pragma unroll
  for (int i = 0; i < 4; ++i) {
    const float* g = GI + (size_t)(kc * 16 + bq * 4 + i) * RTOT;
    pg[i*3+0] = g[jg]; pg[i*3+1] = g[256 + jg]; pg[i*3+2] = g[512 + jg];
  }
  for (int t = 0; t < TT; ++t) {
    float* cur = sm + (size_t)(t & 1) * (16 * RS);
    const int fx = tid * 8, bb = fx >> 8, off = fx & 255;
    if (t > 0) {
      const unsigned tg = (unsigned)t;
      unsigned f0 = agld(flags + l), f1 = agld(flags + 64 + l);
      while (!__all(f0 >= tg && f1 >= tg)) { f0 = agld(flags + l); f1 = agld(flags + 64 + l); }
      __asm__ __volatile__("" ::: "memory");
      const ull* rp = (const ull*)(ring + (size_t)((t - 1) & 3) * 4096);
      const ull v0 = agld8(rp + tid * 4 + 0);
      const ull v1 = agld8(rp + tid * 4 + 1);
      const ull v2 = agld8(rp + tid * 4 + 2);
      const ull v3 = agld8(rp + tid * 4 + 3);
      *(float4*)(cur + bb * RS + off) = make_float4(
          __uint_as_float((unsigned)v0), __uint_as_float((unsigned)(v0 >> 32)),
          __uint_as_float((unsigned)v1), __uint_as_float((unsigned)(v1 >> 32)));
      *(float4*)(cur + bb * RS + off + 4) = make_float4(
          __uint_as_float((unsigned)v2), __uint_as_float((unsigned)(v2 >> 32)),
          __uint_as_float((unsigned)v3), __uint_as_float((unsigned)(v3 >> 32)));
    } else {
      *(float4*)(cur + bb * RS + off)     = make_float4(0.f, 0.f, 0.f, 0.f);
      *(float4*)(cur + bb * RS + off + 4) = make_float4(0.f, 0.f, 0.f, 0.f);
    }
    __syncthreads();
    const int sl = t & 7;
    float gr[4], gz[4], gn[4];
    const int src = (l & 56) + sl;
#pragma unroll
    for (int i = 0; i < 4; ++i) {
      gr[i] = __shfl(pg[i*3+0], src);
      gz[i] = __shfl(pg[i*3+1], src);
      gn[i] = __shfl(pg[i*3+2], src);
    }
    float ar[4] = {0,0,0,0}, az[4] = {0,0,0,0}, an[4] = {0,0,0,0};
#pragma unroll
    for (int i = 0; i < 4; ++i) {
      const float* base = cur + (bq * 4 + i) * RS;
#pragma unroll
      for (int i4 = 0; i4 < 8; ++i4) {
        const float4 h4 = *(const float4*)(base + kc * 32 + i4 * 4);
        ar[i] = fmaf(wr[i4].x, h4.x, ar[i]); ar[i] = fmaf(wr[i4].y, h4.y, ar[i]);
        ar[i] = fmaf(wr[i4].z, h4.z, ar[i]); ar[i] = fmaf(wr[i4].w, h4.w, ar[i]);
        az[i] = fmaf(wz[i4].x, h4.x, az[i]); az[i] = fmaf(wz[i4].y, h4.y, az[i]);
        az[i] = fmaf(wz[i4].z, h4.z, az[i]); az[i] = fmaf(wz[i4].w, h4.w, az[i]);
        an[i] = fmaf(wn[i4].x, h4.x, an[i]); an[i] = fmaf(wn[i4].y, h4.y, an[i]);
        an[i] = fmaf(wn[i4].z, h4.z, an[i]); an[i] = fmaf(wn[i4].w, h4.w, an[i]);
      }
    }
#pragma unroll
    for (int off2 = 4; off2; off2 >>= 1) {
#pragma unroll
      for (int i = 0; i < 4; ++i) {
        ar[i] += __shfl_down(ar[i], off2);
        az[i] += __shfl_down(az[i], off2);
        an[i] += __shfl_down(an[i], off2);
      }
    }
    if (kc == 0) {
#pragma unroll
      for (int i = 0; i < 4; ++i) {
        const int b = bq * 4 + i;
        const float hprev = cur[b * RS + jg];
        const float rg = sigm(gr[i] + gbr + ar[i]);
        const float zg = sigm(gz[i] + gbz + az[i]);
        const float nn = tanhf(gn[i] + rg * (an[i] + gbn));
        const float hn = (1.f - zg) * nn + zg * hprev;
        hs[(size_t)t * 4096 + b * 256 + jg] = hn;
        agstf(ring + (size_t)(t & 3) * 4096 + b * 256 + jg, hn);
      }
    }
    __asm__ __volatile__("s_waitcnt vmcnt(0)" ::: "memory");
    if (l == 0) agstu(flags + wg * 8 + w, (unsigned)(t + 1));
    if (sl == 7 && t + 1 < TT) {
      int s = t + 1 + kc; if (s > TT - 1) s = TT - 1;
#pragma unroll
      for (int i = 0; i < 4; ++i) {
        const float* g = GI + (size_t)(s * 16 + bq * 4 + i) * RTOT;
        pg[i*3+0] = g[jg]; pg[i*3+1] = g[256 + jg]; pg[i*3+2] = g[512 + jg];
      }
    }
  }
}

// E1: single WG x 512 on XCD3, barrier-free LDS exchange with per-wave flags.
__device__ void e1_scan(const float* __restrict__ GIe, const float* __restrict__ whh,
                        const float* __restrict__ bhh, float* __restrict__ hall,
                        float* __restrict__ sm)
{
  volatile int* wf = (volatile int*)(sm + 256);    // 8 wave flags
  const int tid = threadIdx.x;
  const int l = tid & 63, w = tid >> 6;
  const int j = tid >> 2, kc = tid & 3;            // 128 outputs, 4 lanes each
  float4 wr[8], wz[8], wn[8];
#pragma unroll
  for (int i4 = 0; i4 < 8; ++i4) {
    const int kk = kc * 32 + i4 * 4;
    wr[i4] = *(const float4*)(whh + (size_t)j * 128 + kk);
    wz[i4] = *(const float4*)(whh + (size_t)(128 + j) * 128 + kk);
    wn[i4] = *(const float4*)(whh + (size_t)(256 + j) * 128 + kk);
  }
  const float gbr = bhh[j], gbz = bhh[128 + j], gbn = bhh[256 + j];
  float pgr, pgz, pgn;
  { const float* g = GIe + (size_t)kc * RTOT;
    pgr = g[j]; pgz = g[128 + j]; pgn = g[256 + j]; }
  if (tid < 128) sm[tid] = 0.f;                    // buf0 = h_{-1}
  if (tid < 8) wf[tid] = 0;
  __syncthreads();                                 // one-time init barrier

  for (int t = 0; t < NTOK; ++t) {
    const float* cur = sm + (t & 1) * 128;
    if (t > 0) {
      int v = wf[l & 7];
      while (!__all(v >= t)) v = wf[l & 7];
      __asm__ __volatile__("" ::: "memory");
    }
    const int sl = t & 3;
    const float gr = __shfl(pgr, (l & 60) + sl);
    const float gz = __shfl(pgz, (l & 60) + sl);
    const float gn = __shfl(pgn, (l & 60) + sl);
    float pr = 0.f, pz = 0.f, pn = 0.f;
#pragma unroll
    for (int i4 = 0; i4 < 8; ++i4) {
      const float4 h4 = *(const float4*)(cur + kc * 32 + i4 * 4);
      pr = fmaf(wr[i4].x, h4.x, pr); pr = fmaf(wr[i4].y, h4.y, pr);
      pr = fmaf(wr[i4].z, h4.z, pr); pr = fmaf(wr[i4].w, h4.w, pr);
      pz = fmaf(wz[i4].x, h4.x, pz); pz = fmaf(wz[i4].y, h4.y, pz);
      pz = fmaf(wz[i4].z, h4.z, pz); pz = fmaf(wz[i4].w, h4.w, pz);
      pn = fmaf(wn[i4].x, h4.x, pn); pn = fmaf(wn[i4].y, h4.y, pn);
      pn = fmaf(wn[i4].z, h4.z, pn); pn = fmaf(wn[i4].w, h4.w, pn);
    }
#pragma unroll
    for (int off = 2; off; off >>= 1) {
      pr += __shfl_down(pr, off); pz += __shfl_down(pz, off); pn += __shfl_down(pn, off);
    }
    if (kc == 0) {
      const float hprev = cur[j];
      const float rg = sigm(gr + gbr + pr);
      const float zg = sigm(gz + gbz + pz);
      const float nn = tanhf(gn + rg * (pn + gbn));
      const float hn = (1.f - zg) * nn + zg * hprev;
      sm[((t + 1) & 1) * 128 + j] = hn;            // h_t -> other buffer
      hall[(size_t)t * 128 + j] = hn;
    }
    __asm__ __volatile__("s_waitcnt lgkmcnt(0)" ::: "memory");  // ds_write done
    if (l == 0) wf[w] = t + 1;                     // in-order per-wave LDS publish
    if (sl == 3 && t + 1 < NTOK) {
      int s = t + 1 + kc; if (s > NTOK - 1) s = NTOK - 1;
      const float* g = GIe + (size_t)s * RTOT;
      pgr = g[j]; pgz = g[128 + j]; pgn = g[256 + j];
    }
  }
}

__global__ __launch_bounds__(512, 2) void scan_kernel(ScanArgs A)
{
  // 84 KiB LDS blocker (R6-verified non-elidable via dynamic index): 1 WG/CU,
  // so any running role WG is alone on its CU. Also hosts staging/E1 buffers.
  __shared__ float sm[21504];
  __shared__ int role_s[2];
  if (threadIdx.x == 0) {
    unsigned x;
    asm volatile("s_getreg_b32 %0, hwreg(HW_REG_XCC_ID)" : "=s"(x));
    const int xcd = (int)(x & 7u);
    role_s[0] = xcd;
    const int r = atomicAdd(A.cnt + xcd, 1);
    role_s[1] = r;
    ((volatile float*)sm)[(r * 97 + xcd * 13) % 21504] = 0.f;
  }
  __syncthreads();
  const int xcd = role_s[0], r = role_s[1];
  if (xcd == 0)      { if (r < 16) expert_scan<512, 16>(A.GI + E3OFF, A.w3, A.b3, A.ha3, A.ring3, A.f3, sm, r); }
  else if (xcd == 1) { if (r < 16) router_scan(A.GI, A.rwhh, A.rbhh, A.hs, A.ringR, A.fR, sm, r); }
  else if (xcd == 2) { if (r < 8)  expert_scan<256, 8>(A.GI + E2OFF, A.w2, A.b2, A.ha2, A.ring2, A.f2, sm, r); }
  else if (xcd == 3) { if (r < 1)  e1_scan(A.GI + E1OFF, A.w1, A.b1, A.ha1, sm); }
}

// ================= phase 3a: router head, softmax, eul/task atomics =================
__global__ __launch_bounds__(256) void router_out_kernel(
    const float* __restrict__ hs, const float* __restrict__ ow, const float* __restrict__ ob,
    const int* __restrict__ tids, float* __restrict__ raw_out,
    float* __restrict__ tsum, float* __restrict__ tcnt)
{
  const int tid = threadIdx.x;
  const int lane = tid & 63, w = tid >> 6;
  const int n = blockIdx.x * 4 + w;
  float s0 = 0.f, s1 = 0.f, s2 = 0.f, s3 = 0.f;
#pragma unroll
  for (int q = 0; q < 4; ++q) {
    const int jj = lane + q * 64;
    float h = hs[(size_t)n * 256 + jj];
    h = h > 0.f ? h : 0.f;
    s0 = fmaf(h, ow[jj], s0);
    s1 = fmaf(h, ow[256 + jj], s1);
    s2 = fmaf(h, ow[512 + jj], s2);
    s3 = fmaf(h, ow[768 + jj], s3);
  }
  for (int off = 32; off; off >>= 1) {
    s0 += __shfl_xor(s0, off); s1 += __shfl_xor(s1, off);
    s2 += __shfl_xor(s2, off); s3 += __shfl_xor(s3, off);
  }
  if (lane == 0) {
    const float l0 = s0 + ob[0], l1 = s1 + ob[1], l2 = s2 + ob[2], l3 = s3 + ob[3];
    const float m = fmaxf(fmaxf(l0, l1), fmaxf(l2, l3));
    const float e0 = expf(l0 - m), e1 = expf(l1 - m), e2 = expf(l2 - m), e3 = expf(l3 - m);
    const float inv = 1.f / (e0 + e1 + e2 + e3);
    float4 rv; rv.x = e0 * inv; rv.y = e1 * inv; rv.z = e2 * inv; rv.w = e3 * inv;
    *(float4*)(raw_out + (size_t)n * 4) = rv;
    const float eul = rv.y * 128.f + rv.z * 256.f + rv.w * 512.f;
    const int tk = tids[n];
    atomicAdd(&tsum[tk], eul);
    atomicAdd(&tcnt[tk], 1.f);
  }
}

// ================= phase 3b: BN stats per column =================
__global__ __launch_bounds__(256) void bn_stats_kernel(
    const float* __restrict__ h1, const float* __restrict__ h2, const float* __restrict__ h3,
    float* __restrict__ mu, float* __restrict__ rstd)
{
  const int c = blockIdx.x;
  const float* hp; int He, hc;
  if (c < 128)      { hp = h1; He = 128; hc = c; }
  else if (c < 384) { hp = h2; He = 256; hc = c - 128; }
  else              { hp = h3; He = 512; hc = c - 384; }
  float s = 0.f, s2 = 0.f;
  for (int r = threadIdx.x; r < NTOK; r += 256) {
    const float v = hp[(size_t)r * He + hc];
    s += v; s2 = fmaf(v, v, s2);
  }
  for (int off = 32; off; off >>= 1) { s += __shfl_xor(s, off); s2 += __shfl_xor(s2, off); }
  __shared__ float red[8];
  const int lane = threadIdx.x & 63, w = threadIdx.x >> 6;
  if (lane == 0) { red[w] = s; red[4 + w] = s2; }
  __syncthreads();
  if (threadIdx.x == 0) {
    const float S = red[0] + red[1] + red[2] + red[3];
    const float S2 = red[4] + red[5] + red[6] + red[7];
    const float m = S * (1.f / 4096.f);
    float v = S2 * (1.f / 4096.f) - m * m;
    v = v > 0.f ? v : 0.f;
    mu[c] = m;
    rstd[c] = 1.f / sqrtf(v + 1e-5f);
  }
}

// ================= phase 3c: A' = gate * relu(bn(h)); plus task losses =================
__global__ __launch_bounds__(256) void aprime_kernel(
    const float* __restrict__ h1, const float* __restrict__ h2, const float* __restrict__ h3,
    const float* __restrict__ g1, const float* __restrict__ be1,
    const float* __restrict__ g2, const float* __restrict__ be2,
    const float* __restrict__ g3, const float* __restrict__ be3,
    const float* __restrict__ mu, const float* __restrict__ rstd,
    const float* __restrict__ raw, float* __restrict__ Ap,
    const float* __restrict__ tsum, const float* __restrict__ tcnt, float* __restrict__ tl_out)
{
  if (blockIdx.x == 4096) {
    if (threadIdx.x < 4) tl_out[threadIdx.x] = tsum[threadIdx.x] / tcnt[threadIdx.x];
    return;
  }
  const int n = blockIdx.x;
  for (int c = threadIdx.x; c < 896; c += 256) {
    const float* hp; const float* gg; const float* bb; int He, hc, e;
    if (c < 128)      { hp = h1; gg = g1; bb = be1; He = 128; hc = c;       e = 1; }
    else if (c < 384) { hp = h2; gg = g2; bb = be2; He = 256; hc = c - 128; e = 2; }
    else              { hp = h3; gg = g3; bb = be3; He = 512; hc = c - 384; e = 3; }
    const float h = hp[(size_t)n * He + hc];
    float v = (h - mu[c]) * rstd[c] * gg[hc] + bb[hc];
    v = v > 0.f ? v : 0.f;
    Ap[(size_t)n * 896 + c] = raw[(size_t)n * 4 + e] * v;
  }
}

// ================= phase 4: out = A' @ OWc^T + gated biases + g0*x =================
__global__ __launch_bounds__(256) void out_gemm_kernel(
    const float* __restrict__ Ap,
    const float* __restrict__ ow1, const float* __restrict__ ow2, const float* __restrict__ ow3,
    const float* __restrict__ ob1, const float* __restrict__ ob2, const float* __restrict__ ob3,
    const float* __restrict__ X, const float* __restrict__ raw, float* __restrict__ out)
{
  __shared__ float At[32*64];
  __shared__ float Bt[32*64];
  const int n0 = blockIdx.x * 64;
  const int d0 = blockIdx.y * 64;
  const int tid = threadIdx.x;
  const int lm = tid & 63, lk4 = tid >> 6;
  const int tx = tid & 15, ty = tid >> 4;
  float acc[4][4];
#pragma unroll
  for (int i = 0; i < 4; ++i)
#pragma unroll
    for (int q = 0; q < 4; ++q) acc[i][q] = 0.f;

  for (int kb = 0; kb < 896; kb += 32) {
    const float* W; int He, ko;
    if (kb < 128)      { W = ow1; He = 128; ko = 0; }
    else if (kb < 384) { W = ow2; He = 256; ko = 128; }
    else               { W = ow3; He = 512; ko = 384; }
    const float4 a0 = *(const float4*)(Ap + (size_t)(n0+lm)*896 + kb + lk4*8);
    const float4 a1 = *(const float4*)(Ap + (size_t)(n0+lm)*896 + kb + lk4*8 + 4);
    const float4 c0 = *(const float4*)(W + (size_t)(d0+lm)*He + (kb - ko) + lk4*8);
    const float4 c1 = *(const float4*)(W + (size_t)(d0+lm)*He + (kb - ko) + lk4*8 + 4);
    __syncthreads();
    At[(lk4*8+0)*64+lm]=a0.x; At[(lk4*8+1)*64+lm]=a0.y; At[(lk4*8+2)*64+lm]=a0.z; At[(lk4*8+3)*64+lm]=a0.w;
    At[(lk4*8+4)*64+lm]=a1.x; At[(lk4*8+5)*64+lm]=a1.y; At[(lk4*8+6)*64+lm]=a1.z; At[(lk4*8+7)*64+lm]=a1.w;
    Bt[(lk4*8+0)*64+lm]=c0.x; Bt[(lk4*8+1)*64+lm]=c0.y; Bt[(lk4*8+2)*64+lm]=c0.z; Bt[(lk4*8+3)*64+lm]=c0.w;
    Bt[(lk4*8+4)*64+lm]=c1.x; Bt[(lk4*8+5)*64+lm]=c1.y; Bt[(lk4*8+6)*64+lm]=c1.z; Bt[(lk4*8+7)*64+lm]=c1.w;
    __syncthreads();
#pragma unroll
    for (int k = 0; k < 32; ++k) {
      const float4 av = *(const float4*)&At[k*64 + ty*4];
      const float4 bv = *(const float4*)&Bt[k*64 + tx*4];
      acc[0][0]=fmaf(av.x,bv.x,acc[0][0]); acc[0][1]=fmaf(av.x,bv.y,acc[0][1]); acc[0][2]=fmaf(av.x,bv.z,acc[0][2]); acc[0][3]=fmaf(av.x,bv.w,acc[0][3]);
      acc[1][0]=fmaf(av.y,bv.x,acc[1][0]); acc[1][1]=fmaf(av.y,bv.y,acc[1][1]); acc[1][2]=fmaf(av.y,bv.z,acc[1][2]); acc[1][3]=fmaf(av.y,bv.w,acc[1][3]);
      acc[2][0]=fmaf(av.z,bv.x,acc[2][0]); acc[2][1]=fmaf(av.z,bv.y,acc[2][1]); acc[2][2]=fmaf(av.z,bv.z,acc[2][2]); acc[2][3]=fmaf(av.z,bv.w,acc[2][3]);
      acc[3][0]=fmaf(av.w,bv.x,acc[3][0]); acc[3][1]=fmaf(av.w,bv.y,acc[3][1]); acc[3][2]=fmaf(av.w,bv.z,acc[3][2]); acc[3][3]=fmaf(av.w,bv.w,acc[3][3]);
    }
  }
#pragma unroll
  for (int i = 0; i < 4; ++i) {
    const int n = n0 + ty * 4 + i;
    const float4 g  = *(const float4*)(raw + (size_t)n * 4);
    const float4 xv = *(const float4*)(X + (size_t)n * 512 + d0 + tx * 4);
    const float4 o1 = *(const float4*)(ob1 + d0 + tx * 4);
    const float4 o2 = *(const float4*)(ob2 + d0 + tx * 4);
    const float4 o3 = *(const float4*)(ob3 + d0 + tx * 4);
    float4 o;
    o.x = acc[i][0] + g.x*xv.x + g.y*o1.x + g.z*o2.x + g.w*o3.x;
    o.y = acc[i][1] + g.x*xv.y + g.y*o1.y + g.z*o2.y + g.w*o3.y;
    o.z = acc[i][2] + g.x*xv.z + g.y*o1.z + g.z*o2.z + g.w*o3.z;
    o.w = acc[i][3] + g.x*xv.w + g.y*o1.w + g.z*o2.w + g.w*o3.w;
    *(float4*)(out + (size_t)n * 512 + d0 + tx * 4) = o;
  }
}

// ================= host =================
extern "C" void kernel_launch(void* const* d_in, const int* in_sizes, int n_in,
                              void* d_out, int out_size, void* d_ws, size_t ws_size,
                              hipStream_t stream) {
  const float* x    = (const float*)d_in[0];
  const int*   tids = (const int*)d_in[1];
  const float* rwih = (const float*)d_in[2];
  const float* rwhh = (const float*)d_in[3];
  const float* rbih = (const float*)d_in[4];
  const float* rbhh = (const float*)d_in[5];
  const float* row  = (const float*)d_in[6];
  const float* rob  = (const float*)d_in[7];
  const float* w1ih = (const float*)d_in[8];
  const float* w1hh = (const float*)d_in[9];
  const float* b1ih = (const float*)d_in[10];
  const float* b1hh = (const float*)d_in[11];
  const float* bn1g = (const float*)d_in[12];
  const float* bn1b = (const float*)d_in[13];
  const float* ow1  = (const float*)d_in[14];
  const float* ob1  = (const float*)d_in[15];
  const float* w2ih = (const float*)d_in[16];
  const float* w2hh = (const float*)d_in[17];
  const float* b2ih = (const float*)d_in[18];
  const float* b2hh = (const float*)d_in[19];
  const float* bn2g = (const float*)d_in[20];
  const float* bn2b = (const float*)d_in[21];
  const float* ow2  = (const float*)d_in[22];
  const float* ob2  = (const float*)d_in[23];
  const float* w3ih = (const float*)d_in[24];
  const float* w3hh = (const float*)d_in[25];
  const float* b3ih = (const float*)d_in[26];
  const float* b3hh = (const float*)d_in[27];
  const float* bn3g = (const float*)d_in[28];
  const float* bn3b = (const float*)d_in[29];
  const float* ow3  = (const float*)d_in[30];
  const float* ob3  = (const float*)d_in[31];

  char* ws = (char*)d_ws;
  float*    tsum  = (float*)(ws + OFF_TSUM);
  float*    tcnt  = (float*)(ws + OFF_TCNT);
  int*      cnt   = (int*)(ws + OFF_CNT);
  unsigned* f3    = (unsigned*)(ws + OFF_F3);
  unsigned* fR    = (unsigned*)(ws + OFF_FR);
  unsigned* f2    = (unsigned*)(ws + OFF_F2);
  float*    ring3 = (float*)(ws + OFF_RING3);
  float*    ring2 = (float*)(ws + OFF_RING2);
  float*    ringR = (float*)(ws + OFF_RINGR);
  float*    GI    = (float*)(ws + OFF_GI);
  float*    hs    = (float*)(ws + OFF_HS);
  float*    ha3   = (float*)(ws + OFF_HA3);
  float*    ha2   = (float*)(ws + OFF_HA2);
  float*    ha1   = (float*)(ws + OFF_HA1);
  float*    Ap    = (float*)(ws + OFF_AP);
  float*    mu    = (float*)(ws + OFF_MU);
  float*    rstd  = (float*)(ws + OFF_RSTD);

  float* outp = (float*)d_out;
  float* rawp = outp + (size_t)NTOK * DD;
  float* tlp  = rawp + (size_t)NTOK * 4;

  // zero claim counters, task accumulators, and all wave flags
  hipMemsetAsync(ws, 0, ZBYTES, stream);

  // phase 1: input projections for router + all experts
  gemm1_kernel<<<dim3(64, 54), 256, 0, stream>>>(x, rwih, w1ih, w2ih, w3ih,
                                                 rbih, b1ih, b2ih, b3ih, GI);

  // phase 2: XCD-claimed scans; fence-free sc0 flag/ring protocol; 1 WG/CU
  ScanArgs sa;
  sa.GI = GI;
  sa.rwhh = rwhh; sa.rbhh = rbhh; sa.hs = hs;  sa.ringR = ringR; sa.fR = fR;
  sa.w1 = w1hh;   sa.b1 = b1hh;   sa.ha1 = ha1;
  sa.w2 = w2hh;   sa.b2 = b2hh;   sa.ha2 = ha2; sa.ring2 = ring2; sa.f2 = f2;
  sa.w3 = w3hh;   sa.b3 = b3hh;   sa.ha3 = ha3; sa.ring3 = ring3; sa.f3 = f3;
  sa.cnt = cnt;
  scan_kernel<<<dim3(384), dim3(512), 0, stream>>>(sa);

  // phase 3: router head + task-loss atomics; BN stats; A' build (+ task losses)
  router_out_kernel<<<dim3(1024), 256, 0, stream>>>(hs, row, rob, tids, rawp, tsum, tcnt);
  bn_stats_kernel<<<dim3(896), 256, 0, stream>>>(ha1, ha2, ha3, mu, rstd);
  aprime_kernel<<<dim3(4097), 256, 0, stream>>>(ha1, ha2, ha3, bn1g, bn1b, bn2g, bn2b,
                                                bn3g, bn3b, mu, rstd, rawp, Ap,
                                                tsum, tcnt, tlp);

  // phase 4: gated expert-output GEMM + identity expert + gated biases
  out_gemm_kernel<<<dim3(64, 8), 256, 0, stream>>>(Ap, ow1, ow2, ow3, ob1, ob2, ob3,
                                                   x, rawp, outp);
}